// Round 8
// baseline (2983.998 us; speedup 1.0000x reference)
//
#include <hip/hip_runtime.h>

#define NN   100000
#define EE   3200000
#define DIN  83
#define DHID 1024
#define NCLS 25
#define XPAD 96    // x/ax bf16 row padding (192 B = 3 cache lines)
#define ZPAD 32    // z bf16 row padding (64 B = 1 cache line)

#define NBK     391   // buckets of 256 rows (row >> 8)
#define CHUNK   8192  // edges per partition block

typedef __attribute__((__ext_vector_type__(8))) short sh8;
typedef __attribute__((__ext_vector_type__(4))) float f4_t;

static __device__ __forceinline__ float relu_(float v) { return v > 0.f ? v : 0.f; }

// f32 -> bf16 (RNE)
static __device__ __forceinline__ unsigned short f2bf(float f) {
  unsigned int u = __float_as_uint(f);
  unsigned int r = u + 0x7FFFu + ((u >> 16) & 1u);
  return (unsigned short)(r >> 16);
}
// packed bf16 pair -> two f32
static __device__ __forceinline__ float bflo(unsigned int q) {
  return __uint_as_float(q << 16);
}
static __device__ __forceinline__ float bfhi(unsigned int q) {
  return __uint_as_float(q & 0xFFFF0000u);
}

// K1: Conv1d(1->4,k5,p2) + channel-sum + bias + relu -> bf16 x[NN][96]
__global__ void conv_relu_k(const float* __restrict__ feature,
                            const float* __restrict__ conv_w,
                            const float* __restrict__ conv_b,
                            unsigned short* __restrict__ x) {
  float ws0 = conv_w[0] + conv_w[5] + conv_w[10] + conv_w[15];
  float ws1 = conv_w[1] + conv_w[6] + conv_w[11] + conv_w[16];
  float ws2 = conv_w[2] + conv_w[7] + conv_w[12] + conv_w[17];
  float ws3 = conv_w[3] + conv_w[8] + conv_w[13] + conv_w[18];
  float ws4 = conv_w[4] + conv_w[9] + conv_w[14] + conv_w[19];
  float bs  = conv_b[0] + conv_b[1] + conv_b[2] + conv_b[3];
  const int total = NN * XPAD;
  for (int idx = blockIdx.x * blockDim.x + threadIdx.x; idx < total;
       idx += gridDim.x * blockDim.x) {
    int n = idx / XPAD;
    int i = idx - n * XPAD;
    unsigned short o = 0;
    if (i < DIN) {
      const float* f = feature + (size_t)n * DIN;
      float acc = bs;
      if (i >= 2)      acc += ws0 * f[i - 2];
      if (i >= 1)      acc += ws1 * f[i - 1];
      acc += ws2 * f[i];
      if (i + 1 < DIN) acc += ws3 * f[i + 1];
      if (i + 2 < DIN) acc += ws4 * f[i + 2];
      o = f2bf(relu_(acc));
    }
    x[idx] = o;
  }
}

__global__ void zero_int_k(int* __restrict__ p, int total) {
  for (int i = blockIdx.x * blockDim.x + threadIdx.x; i < total;
       i += gridDim.x * blockDim.x)
    p[i] = 0;
}

// W1[83,1024] f32 -> w1t[1024][96] bf16 (transposed, K zero-padded)
__global__ void w1t_k(const float* __restrict__ W1, unsigned short* __restrict__ w1t) {
  int idx = blockIdx.x * blockDim.x + threadIdx.x;
  if (idx >= DHID * XPAD) return;
  int k = idx / DHID;
  int n = idx - k * DHID;
  float v = (k < DIN) ? W1[k * DHID + n] : 0.f;
  w1t[n * XPAD + k] = f2bf(v);
}

// W2[1024,25] f32 -> w2t[32][1024] bf16 (transposed, N zero-padded)
__global__ void w2t_k(const float* __restrict__ W2, unsigned short* __restrict__ w2t) {
  int idx = blockIdx.x * blockDim.x + threadIdx.x;
  if (idx >= 32 * DHID) return;
  int k = idx / 32;
  int n = idx - k * 32;
  float v = (n < NCLS) ? W2[k * NCLS + n] : 0.f;
  w2t[n * DHID + k] = f2bf(v);
}

// ---- bucket structure build ----

// Per-block LDS histogram over 391 buckets; one global atomic per bucket/block
// (gbk line-padded stride 16 to avoid same-line atomic pileup).
__global__ __launch_bounds__(256) void bucket_hist_k(
    const int* __restrict__ row, int* __restrict__ gbk) {
  __shared__ int cnt[NBK];
  const int tid = threadIdx.x;
  for (int b = tid; b < NBK; b += 256) cnt[b] = 0;
  __syncthreads();
  const int cb = blockIdx.x * CHUNK;
  const int csize = (cb + CHUNK <= EE) ? CHUNK : (EE - cb);
  for (int i = tid; i < csize; i += 256)
    atomicAdd(&cnt[row[cb + i] >> 8], 1);
  __syncthreads();
  for (int b = tid; b < NBK; b += 256)
    if (cnt[b]) atomicAdd(&gbk[b * 16], cnt[b]);
}

// Single-block scan of bucket totals -> bucket bases (+ seed partition cursors)
__global__ void scan_buckets_k(const int* __restrict__ gbk,
                               int* __restrict__ bbase, int* __restrict__ gcur) {
  __shared__ int sd[512];
  int t = threadIdx.x;
  int v = (t < NBK) ? gbk[t * 16] : 0;
  sd[t] = v;
  __syncthreads();
  for (int off = 1; off < 512; off <<= 1) {
    int add = (t >= off) ? sd[t - off] : 0;
    __syncthreads();
    sd[t] += add;
    __syncthreads();
  }
  if (t < NBK) {
    int excl = sd[t] - v;
    bbase[t] = excl;
    gcur[t * 16] = excl;   // line-padded cursor
  }
  if (t == 0) bbase[NBK] = EE;
}

// Partition edges into 391 buckets (row>>8), bucket-major tmp.
// tmp.x = col | (row&255)<<17 ; tmp.y = bits(val)
__global__ __launch_bounds__(256) void partition_k(
    const float* __restrict__ vals, const int* __restrict__ row,
    const int* __restrict__ col, int* __restrict__ gcur,
    int2* __restrict__ tmp) {
  __shared__ int cnt[NBK];
  __shared__ int sc[512];     // scan scratch
  __shared__ int es[NBK];     // exclusive start per bucket
  __shared__ int lcur[NBK];
  __shared__ int gbase[NBK];
  __shared__ int2 staged[CHUNK];
  const int tid = threadIdx.x;
  const int cb = blockIdx.x * CHUNK;
  const int csize = (cb + CHUNK <= EE) ? CHUNK : (EE - cb);

  for (int b = tid; b < NBK; b += 256) cnt[b] = 0;
  __syncthreads();
  for (int i = tid; i < csize; i += 256)
    atomicAdd(&cnt[row[cb + i] >> 8], 1);
  __syncthreads();
  sc[tid]       = (tid < NBK) ? cnt[tid] : 0;
  sc[tid + 256] = (tid + 256 < NBK) ? cnt[tid + 256] : 0;
  __syncthreads();
  for (int off = 1; off < 512; off <<= 1) {
    int a0 = (tid >= off) ? sc[tid - off] : 0;
    int a1 = (tid + 256 >= off) ? sc[tid + 256 - off] : 0;
    __syncthreads();
    sc[tid] += a0;
    sc[tid + 256] += a1;
    __syncthreads();
  }
  for (int b = tid; b < NBK; b += 256) {
    int e = sc[b] - cnt[b];   // exclusive
    es[b] = e;
    lcur[b] = e;
  }
  __syncthreads();
  for (int b = tid; b < NBK; b += 256)
    gbase[b] = cnt[b] ? atomicAdd(&gcur[b * 16], cnt[b]) : 0;
  __syncthreads();
  for (int i = tid; i < csize; i += 256) {
    int r = row[cb + i];
    int lpos = atomicAdd(&lcur[r >> 8], 1);
    staged[lpos] = make_int2(col[cb + i] | ((r & 255) << 17),
                             __float_as_int(vals[cb + i]));
  }
  __syncthreads();
  for (int j = tid; j < csize; j += 256) {
    int lo = 0, hi = NBK - 1;          // largest b with es[b] <= j
    while (lo < hi) {
      int mid = (lo + hi + 1) >> 1;
      if (es[mid] <= j) lo = mid; else hi = mid - 1;
    }
    tmp[gbase[lo] + (j - es[lo])] = staged[j];
  }
}

// ---- SpMM D=83 directly from bucket-major tmp, LDS f32 accumulators ----
// grid 782 = (bucket, half). Block: 512 thr, acc[128][96] f32 = 48 KB.
__global__ __launch_bounds__(512) void spmm83_tmp_k(
    const int* __restrict__ bbase, const int2* __restrict__ tmp,
    const unsigned short* __restrict__ x, unsigned short* __restrict__ ax) {
  __shared__ float acc[128 * 96];   // 48 KB
  const int tid = threadIdx.x;
  const int b = blockIdx.x >> 1;
  const int h = blockIdx.x & 1;
  const int gstart = bbase[b];
  const int nedge = bbase[b + 1] - gstart;
  for (int i = tid; i < 128 * 96; i += 512) acc[i] = 0.f;
  __syncthreads();

  const int w = tid >> 6;
  const int lane = tid & 63;
  const bool act = lane < 48;          // 48 lanes x dword = 96 dims
  const int d2 = lane * 2;

  int base = w * 12;
  for (; base + 12 <= nedge; base += 8 * 12) {
    int2 p[12];
    unsigned q[12];
#pragma unroll
    for (int u = 0; u < 12; ++u) p[u] = tmp[gstart + base + u];
#pragma unroll
    for (int u = 0; u < 12; ++u) {
      int rl = (p[u].x >> 17) & 255;
      if (((rl >> 7) == h) && act)
        q[u] = *(const unsigned*)&x[(size_t)(p[u].x & 0x1FFFF) * XPAD + d2];
    }
#pragma unroll
    for (int u = 0; u < 12; ++u) {
      int rl = (p[u].x >> 17) & 255;
      if (((rl >> 7) == h) && act) {
        float v = __int_as_float(p[u].y);
        int rr = (rl & 127) * 96 + d2;
        atomicAdd(&acc[rr],     v * bflo(q[u]));
        atomicAdd(&acc[rr + 1], v * bfhi(q[u]));
      }
    }
  }
  {  // per-wave tail: [base, min(base+12, nedge))
    int e_end = (base + 12 < nedge) ? base + 12 : nedge;
    for (int e = base; e < e_end; ++e) {
      int2 p = tmp[gstart + e];
      int rl = (p.x >> 17) & 255;
      if (((rl >> 7) == h) && act) {
        unsigned q = *(const unsigned*)&x[(size_t)(p.x & 0x1FFFF) * XPAD + d2];
        float v = __int_as_float(p.y);
        int rr = (rl & 127) * 96 + d2;
        atomicAdd(&acc[rr],     v * bflo(q));
        atomicAdd(&acc[rr + 1], v * bfhi(q));
      }
    }
  }
  __syncthreads();

  const int r0 = (b << 8) + (h << 7);
  for (int idx = tid; idx < 128 * 48; idx += 512) {
    int r = idx / 48;
    int c = idx - r * 48;
    int gr = r0 + r;
    if (gr < NN) {
      unsigned o = (unsigned)f2bf(acc[r * 96 + c * 2])
                 | ((unsigned)f2bf(acc[r * 96 + c * 2 + 1]) << 16);
      *(unsigned*)&ax[(size_t)gr * XPAD + c * 2] = o;
    }
  }
}

// ---- SpMM D=25 from tmp, +b2 fused. grid 782, acc[128][32] = 16 KB ----
__global__ __launch_bounds__(512) void spmm25_tmp_k(
    const int* __restrict__ bbase, const int2* __restrict__ tmp,
    const unsigned short* __restrict__ zb, const float* __restrict__ b2,
    float* __restrict__ out) {
  __shared__ float acc[128 * 32];   // 16 KB
  const int tid = threadIdx.x;
  const int b = blockIdx.x >> 1;
  const int h = blockIdx.x & 1;
  const int gstart = bbase[b];
  const int nedge = bbase[b + 1] - gstart;
  for (int i = tid; i < 128 * 32; i += 512) acc[i] = 0.f;
  __syncthreads();

  const int w = tid >> 6;
  const int lane = tid & 63;
  const int g = lane >> 4;             // 4 edges per wave-iteration
  const int d2 = (lane & 15) * 2;      // dims (d2, d2+1) of 32

  int base = w * 16;
  for (; base + 16 <= nedge; base += 8 * 16) {
    int2 p[4];
    unsigned q[4];
#pragma unroll
    for (int u = 0; u < 4; ++u) {
      p[u] = tmp[gstart + base + u * 4 + g];
      int rl = (p[u].x >> 17) & 255;
      if ((rl >> 7) == h)
        q[u] = *(const unsigned*)&zb[(size_t)(p[u].x & 0x1FFFF) * ZPAD + d2];
    }
#pragma unroll
    for (int u = 0; u < 4; ++u) {
      int rl = (p[u].x >> 17) & 255;
      if ((rl >> 7) == h) {
        float v = __int_as_float(p[u].y);
        int rr = (rl & 127) * 32 + d2;
        atomicAdd(&acc[rr],     v * bflo(q[u]));
        atomicAdd(&acc[rr + 1], v * bfhi(q[u]));
      }
    }
  }
  {  // tail: wave slice [base, min(base+16, nedge)), sub-group strides 4
    int e_end = (base + 16 < nedge) ? base + 16 : nedge;
    for (int e = base + g; e < e_end; e += 4) {
      int2 p = tmp[gstart + e];
      int rl = (p.x >> 17) & 255;
      if ((rl >> 7) == h) {
        unsigned q = *(const unsigned*)&zb[(size_t)(p.x & 0x1FFFF) * ZPAD + d2];
        float v = __int_as_float(p.y);
        int rr = (rl & 127) * 32 + d2;
        atomicAdd(&acc[rr],     v * bflo(q));
        atomicAdd(&acc[rr + 1], v * bfhi(q));
      }
    }
  }
  __syncthreads();

  const int r0 = (b << 8) + (h << 7);
  for (int idx = tid; idx < 128 * NCLS; idx += 512) {
    int r = idx / NCLS;
    int d = idx - r * NCLS;
    int gr = r0 + r;
    if (gr < NN) out[(size_t)gr * NCLS + d] = acc[r * 32 + d] + b2[d];
  }
}

// ---- Fused MLP via bf16 MFMA: z = relu(ax@W1+b1)@W2, z -> bf16[NN][32] ----
__global__ __launch_bounds__(256) void fused_mlp_mfma(
    const unsigned short* __restrict__ axg, const unsigned short* __restrict__ w1t,
    const float* __restrict__ b1, const unsigned short* __restrict__ w2t,
    unsigned short* __restrict__ zb) {
  __shared__ __align__(16) unsigned short axs[64 * 104];  // [64][96] pad->104
  __shared__ __align__(16) unsigned short hs[64 * 264];   // [64][256] pad->264
  __shared__ float b1s[DHID];
  const int tid = threadIdx.x;
  const int n0 = blockIdx.x * 64;

  for (int idx = tid; idx < 64 * 12; idx += 256) {   // 12 sh8 chunks per row
    int m = idx / 12;
    int c8 = idx - m * 12;
    int node = n0 + m;
    sh8 v = {0, 0, 0, 0, 0, 0, 0, 0};
    if (node < NN) v = *(const sh8*)&axg[(size_t)node * XPAD + c8 * 8];
    *(sh8*)&axs[m * 104 + c8 * 8] = v;
  }
  for (int i = tid; i < DHID; i += 256) b1s[i] = b1[i];
  __syncthreads();

  const int lane = tid & 63;
  const int w = tid >> 6;
  const int quad = lane >> 4;   // A/B frag: k = quad*8 + j
  const int tn = lane & 15;     // A frag: m; B frag: n; C frag: col
  const int m0 = w * 16;

  sh8 a1[4][3];
#pragma unroll
  for (int mt = 0; mt < 4; ++mt)
#pragma unroll
    for (int kc = 0; kc < 3; ++kc)
      a1[mt][kc] = *(const sh8*)&axs[(mt * 16 + tn) * 104 + kc * 32 + quad * 8];

  f4_t z0 = {0.f, 0.f, 0.f, 0.f}, z1 = {0.f, 0.f, 0.f, 0.f};

  for (int c = 0; c < 4; ++c) {
    const int cb = c * 256;
#pragma unroll
    for (int nti = 0; nti < 4; ++nti) {
      const int nt = w * 4 + nti;
      const int ng = cb + nt * 16 + tn;
      const unsigned short* wr = &w1t[(size_t)ng * XPAD + quad * 8];
      sh8 b0 = *(const sh8*)&wr[0];
      sh8 b1f = *(const sh8*)&wr[32];
      sh8 b2f = *(const sh8*)&wr[64];
      float bias = b1s[ng];
#pragma unroll
      for (int mt = 0; mt < 4; ++mt) {
        f4_t acc = {0.f, 0.f, 0.f, 0.f};
        acc = __builtin_amdgcn_mfma_f32_16x16x32_bf16(a1[mt][0], b0, acc, 0, 0, 0);
        acc = __builtin_amdgcn_mfma_f32_16x16x32_bf16(a1[mt][1], b1f, acc, 0, 0, 0);
        acc = __builtin_amdgcn_mfma_f32_16x16x32_bf16(a1[mt][2], b2f, acc, 0, 0, 0);
#pragma unroll
        for (int r = 0; r < 4; ++r) {
          float v = relu_(acc[r] + bias);          // C: col=tn, row=quad*4+r
          hs[(mt * 16 + quad * 4 + r) * 264 + nt * 16 + tn] = f2bf(v);
        }
      }
    }
    __syncthreads();
#pragma unroll
    for (int kc = 0; kc < 8; ++kc) {
      sh8 a2 = *(const sh8*)&hs[(m0 + tn) * 264 + kc * 32 + quad * 8];
      sh8 bl = *(const sh8*)&w2t[(size_t)tn * DHID + cb + kc * 32 + quad * 8];
      z0 = __builtin_amdgcn_mfma_f32_16x16x32_bf16(a2, bl, z0, 0, 0, 0);
      sh8 bh = *(const sh8*)&w2t[(size_t)(16 + tn) * DHID + cb + kc * 32 + quad * 8];
      z1 = __builtin_amdgcn_mfma_f32_16x16x32_bf16(a2, bh, z1, 0, 0, 0);
    }
    __syncthreads();
  }

#pragma unroll
  for (int r = 0; r < 4; ++r) {
    int node = n0 + m0 + quad * 4 + r;
    if (node < NN) {
      zb[(size_t)node * ZPAD + tn]      = f2bf(z0[r]);
      zb[(size_t)node * ZPAD + 16 + tn] = f2bf(z1[r]);
    }
  }
}

extern "C" void kernel_launch(void* const* d_in, const int* in_sizes, int n_in,
                              void* d_out, int out_size, void* d_ws, size_t ws_size,
                              hipStream_t stream) {
  const float* feature = (const float*)d_in[0];
  const float* conv_w  = (const float*)d_in[1];
  const float* conv_b  = (const float*)d_in[2];
  const float* W1      = (const float*)d_in[3];
  const float* b1      = (const float*)d_in[4];
  const float* W2      = (const float*)d_in[5];
  const float* b2      = (const float*)d_in[6];
  const float* adj     = (const float*)d_in[7];
  const int*   erow    = (const int*)d_in[8];
  const int*   ecol    = (const int*)d_in[9];
  float* out = (float*)d_out;

  char* B = (char*)d_ws;
  size_t o = 0;
  auto alloc = [&](size_t bytes, size_t align) -> void* {
    o = (o + align - 1) & ~(align - 1);
    void* p = B + o;
    o += bytes;
    return p;
  };
  unsigned short* x    = (unsigned short*)alloc((size_t)NN * XPAD * 2, 16);
  unsigned short* ax   = (unsigned short*)alloc((size_t)NN * XPAD * 2, 16);
  unsigned short* zb   = (unsigned short*)alloc((size_t)NN * ZPAD * 2, 16);
  int*   gcur    = (int*)alloc((size_t)NBK * 16 * 4, 64);  // line-padded cursors
  int*   gbk     = (int*)alloc((size_t)NBK * 16 * 4, 64);  // line-padded totals
  int*   bbase   = (int*)alloc((size_t)(NBK + 1) * 4, 16); // bucket bases
  unsigned short* w1t = (unsigned short*)alloc((size_t)DHID * XPAD * 2, 16);
  unsigned short* w2t = (unsigned short*)alloc((size_t)32 * DHID * 2, 16);
  int2*  tmp     = (int2*)alloc((size_t)EE * 8, 16);  // bucket-major edges

  // 1) x = relu(conv_sum(feature)) -> bf16 [NN][96]; weight prep
  conv_relu_k<<<8192, 256, 0, stream>>>(feature, conv_w, conv_b, x);
  w1t_k<<<(DHID * XPAD + 255) / 256, 256, 0, stream>>>(W1, w1t);
  w2t_k<<<(32 * DHID + 255) / 256, 256, 0, stream>>>(W2, w2t);
  // 2) bucket build: hist -> scan -> partition (bucket-major tmp, no fine CSR)
  zero_int_k<<<32, 256, 0, stream>>>(gbk, NBK * 16);
  bucket_hist_k<<<(EE + CHUNK - 1) / CHUNK, 256, 0, stream>>>(erow, gbk);
  scan_buckets_k<<<1, 512, 0, stream>>>(gbk, bbase, gcur);
  partition_k<<<(EE + CHUNK - 1) / CHUNK, 256, 0, stream>>>(adj, erow, ecol, gcur, tmp);
  // 3) ax = A @ x  (gather from tmp, LDS f32 accumulation)
  spmm83_tmp_k<<<NBK * 2, 512, 0, stream>>>(bbase, tmp, x, ax);
  // 4) z = relu(ax @ W1 + b1) @ W2 via bf16 MFMA -> bf16 [NN][32]
  fused_mlp_mfma<<<(NN + 63) / 64, 256, 0, stream>>>(ax, w1t, b1, w2t, zb);
  // 5) out = A @ z + b2  (gather from tmp, LDS f32 accumulation)
  spmm25_tmp_k<<<NBK * 2, 512, 0, stream>>>(bbase, tmp, zb, b2, out);
}

// Round 9
// 504.124 us; speedup vs baseline: 5.9192x; 5.9192x over previous
//
#include <hip/hip_runtime.h>

#define NN   100000
#define EE   3200000
#define DIN  83
#define DHID 1024
#define NCLS 25
#define XPAD 96    // x/ax bf16 row padding (192 B = 3 cache lines)
#define ZPAD 32    // z bf16 row padding (64 B = 1 cache line)

#define NBK     391   // buckets of 256 rows (row >> 8)
#define CHUNK   8192  // edges per partition block

typedef __attribute__((__ext_vector_type__(8))) short sh8;
typedef __attribute__((__ext_vector_type__(4))) float f4_t;

static __device__ __forceinline__ float relu_(float v) { return v > 0.f ? v : 0.f; }

// f32 -> bf16 (RNE)
static __device__ __forceinline__ unsigned short f2bf(float f) {
  unsigned int u = __float_as_uint(f);
  unsigned int r = u + 0x7FFFu + ((u >> 16) & 1u);
  return (unsigned short)(r >> 16);
}
// packed bf16 pair -> two f32
static __device__ __forceinline__ float bflo(unsigned int q) {
  return __uint_as_float(q << 16);
}
static __device__ __forceinline__ float bfhi(unsigned int q) {
  return __uint_as_float(q & 0xFFFF0000u);
}

// K1: Conv1d(1->4,k5,p2) + channel-sum + bias + relu -> bf16 x[NN][96]
__global__ void conv_relu_k(const float* __restrict__ feature,
                            const float* __restrict__ conv_w,
                            const float* __restrict__ conv_b,
                            unsigned short* __restrict__ x) {
  float ws0 = conv_w[0] + conv_w[5] + conv_w[10] + conv_w[15];
  float ws1 = conv_w[1] + conv_w[6] + conv_w[11] + conv_w[16];
  float ws2 = conv_w[2] + conv_w[7] + conv_w[12] + conv_w[17];
  float ws3 = conv_w[3] + conv_w[8] + conv_w[13] + conv_w[18];
  float ws4 = conv_w[4] + conv_w[9] + conv_w[14] + conv_w[19];
  float bs  = conv_b[0] + conv_b[1] + conv_b[2] + conv_b[3];
  const int total = NN * XPAD;
  for (int idx = blockIdx.x * blockDim.x + threadIdx.x; idx < total;
       idx += gridDim.x * blockDim.x) {
    int n = idx / XPAD;
    int i = idx - n * XPAD;
    unsigned short o = 0;
    if (i < DIN) {
      const float* f = feature + (size_t)n * DIN;
      float acc = bs;
      if (i >= 2)      acc += ws0 * f[i - 2];
      if (i >= 1)      acc += ws1 * f[i - 1];
      acc += ws2 * f[i];
      if (i + 1 < DIN) acc += ws3 * f[i + 1];
      if (i + 2 < DIN) acc += ws4 * f[i + 2];
      o = f2bf(relu_(acc));
    }
    x[idx] = o;
  }
}

__global__ void zero_int_k(int* __restrict__ p, int total) {
  for (int i = blockIdx.x * blockDim.x + threadIdx.x; i < total;
       i += gridDim.x * blockDim.x)
    p[i] = 0;
}

// W1[83,1024] f32 -> w1t[1024][96] bf16 (transposed, K zero-padded)
__global__ void w1t_k(const float* __restrict__ W1, unsigned short* __restrict__ w1t) {
  int idx = blockIdx.x * blockDim.x + threadIdx.x;
  if (idx >= DHID * XPAD) return;
  int k = idx / DHID;
  int n = idx - k * DHID;
  float v = (k < DIN) ? W1[k * DHID + n] : 0.f;
  w1t[n * XPAD + k] = f2bf(v);
}

// W2[1024,25] f32 -> w2t[32][1024] bf16 (transposed, N zero-padded)
__global__ void w2t_k(const float* __restrict__ W2, unsigned short* __restrict__ w2t) {
  int idx = blockIdx.x * blockDim.x + threadIdx.x;
  if (idx >= 32 * DHID) return;
  int k = idx / 32;
  int n = idx - k * 32;
  float v = (n < NCLS) ? W2[k * NCLS + n] : 0.f;
  w2t[n * DHID + k] = f2bf(v);
}

// ---- CSR build (bucket-hierarchical) ----

// Per-block LDS histogram over 391 buckets; one global atomic per bucket/block
// (gbk line-padded stride 16).
__global__ __launch_bounds__(256) void bucket_hist_k(
    const int* __restrict__ row, int* __restrict__ gbk) {
  __shared__ int cnt[NBK];
  const int tid = threadIdx.x;
  for (int b = tid; b < NBK; b += 256) cnt[b] = 0;
  __syncthreads();
  const int cb = blockIdx.x * CHUNK;
  const int csize = (cb + CHUNK <= EE) ? CHUNK : (EE - cb);
  for (int i = tid; i < csize; i += 256)
    atomicAdd(&cnt[row[cb + i] >> 8], 1);
  __syncthreads();
  for (int b = tid; b < NBK; b += 256)
    if (cnt[b]) atomicAdd(&gbk[b * 16], cnt[b]);
}

// Single-block scan of bucket totals -> bucket bases (+ seed partition cursors)
__global__ void scan_buckets_k(const int* __restrict__ gbk,
                               int* __restrict__ bbase, int* __restrict__ gcur) {
  __shared__ int sd[512];
  int t = threadIdx.x;
  int v = (t < NBK) ? gbk[t * 16] : 0;
  sd[t] = v;
  __syncthreads();
  for (int off = 1; off < 512; off <<= 1) {
    int add = (t >= off) ? sd[t - off] : 0;
    __syncthreads();
    sd[t] += add;
    __syncthreads();
  }
  if (t < NBK) {
    int excl = sd[t] - v;
    bbase[t] = excl;
    gcur[t * 16] = excl;   // line-padded cursor
  }
  if (t == 0) bbase[NBK] = EE;
}

// Pass 1: partition edges into 391 buckets (row>>8), bucket-major tmp.
// Flush: per-bucket wave-cooperative copy (no per-edge binary search).
__global__ __launch_bounds__(256) void partition_k(
    const float* __restrict__ vals, const int* __restrict__ row,
    const int* __restrict__ col, int* __restrict__ gcur,
    int2* __restrict__ tmp) {
  __shared__ int cnt[NBK];
  __shared__ int sc[512];       // scan scratch
  __shared__ int es[NBK + 1];   // exclusive start per bucket (+end)
  __shared__ int lcur[NBK];
  __shared__ int gbase[NBK];
  __shared__ int2 staged[CHUNK];
  const int tid = threadIdx.x;
  const int cb = blockIdx.x * CHUNK;
  const int csize = (cb + CHUNK <= EE) ? CHUNK : (EE - cb);

  for (int b = tid; b < NBK; b += 256) cnt[b] = 0;
  __syncthreads();
  for (int i = tid; i < csize; i += 256)
    atomicAdd(&cnt[row[cb + i] >> 8], 1);
  __syncthreads();
  sc[tid]       = (tid < NBK) ? cnt[tid] : 0;
  sc[tid + 256] = (tid + 256 < NBK) ? cnt[tid + 256] : 0;
  __syncthreads();
  for (int off = 1; off < 512; off <<= 1) {
    int a0 = (tid >= off) ? sc[tid - off] : 0;
    int a1 = (tid + 256 >= off) ? sc[tid + 256 - off] : 0;
    __syncthreads();
    sc[tid] += a0;
    sc[tid + 256] += a1;
    __syncthreads();
  }
  for (int b = tid; b < NBK; b += 256) {
    int e = sc[b] - cnt[b];   // exclusive
    es[b] = e;
    lcur[b] = e;
  }
  if (tid == 0) es[NBK] = csize;
  __syncthreads();
  for (int b = tid; b < NBK; b += 256)
    gbase[b] = cnt[b] ? atomicAdd(&gcur[b * 16], cnt[b]) : 0;
  __syncthreads();
  for (int i = tid; i < csize; i += 256) {
    int r = row[cb + i];
    int lpos = atomicAdd(&lcur[r >> 8], 1);
    staged[lpos] = make_int2(col[cb + i] | ((r & 255) << 17),
                             __float_as_int(vals[cb + i]));
  }
  __syncthreads();
  // flush: wave w copies buckets w, w+4, ... as contiguous runs
  {
    const int w = tid >> 6;
    const int lane = tid & 63;
    for (int b = w; b < NBK; b += 4) {
      int st = es[b], en = es[b + 1];
      int gb = gbase[b];
      for (int j = st + lane; j < en; j += 64)
        tmp[gb + (j - st)] = staged[j];
    }
  }
}

// Pass 2: per-bucket fine scatter + per-row offset derivation (all in LDS).
__global__ __launch_bounds__(256) void fine_scatter2_k(
    const int* __restrict__ bbase, const int2* __restrict__ tmp,
    int2* __restrict__ csr, int* __restrict__ offs, int* __restrict__ counts) {
  __shared__ int cnt[256];
  __shared__ int sd[256];
  __shared__ int lcur[256];
  const int tid = threadIdx.x;
  const int b = blockIdx.x;
  const int r0 = b * 256;
  const int gstart = bbase[b];
  const int nedge = bbase[b + 1] - gstart;
  cnt[tid] = 0;
  __syncthreads();
  for (int i = tid; i < nedge; i += 256)
    atomicAdd(&cnt[((unsigned)tmp[gstart + i].x) >> 17], 1);
  __syncthreads();
  int v = cnt[tid];
  sd[tid] = v;
  __syncthreads();
  for (int off = 1; off < 256; off <<= 1) {
    int add = (tid >= off) ? sd[tid - off] : 0;
    __syncthreads();
    sd[tid] += add;
    __syncthreads();
  }
  int excl = gstart + sd[tid] - v;
  int r = r0 + tid;
  if (r < NN) {
    offs[r] = excl;
    counts[r] = v;
  }
  lcur[tid] = excl;
  __syncthreads();
  for (int i = tid; i < nedge; i += 256) {
    int2 p = tmp[gstart + i];
    int rl = ((unsigned)p.x) >> 17;
    int pos = atomicAdd(&lcur[rl], 1);
    csr[pos] = make_int2(p.x & 0x1FFFF, p.y);
  }
}

// ---- gather SpMM, D=83(96 bf16): one wave per row, ILP-8 edge unroll ----
__global__ __launch_bounds__(256) void spmm83_g(
    const int* __restrict__ offs, const int* __restrict__ cnt,
    const int2* __restrict__ csr, const unsigned short* __restrict__ x,
    unsigned short* __restrict__ ax) {
  int wave = (int)((blockIdx.x * blockDim.x + threadIdx.x) >> 6);
  int lane = threadIdx.x & 63;
  if (wave >= NN) return;
  int s = offs[wave];
  int n = cnt[wave];
  const bool act = lane < 48;         // 48 lanes x short2 = 96 dims
  const int d2 = lane * 2;
  float a0 = 0.f, a1 = 0.f;
  int i = 0;
  for (; i + 8 <= n; i += 8) {
    int2 p[8];
#pragma unroll
    for (int u = 0; u < 8; ++u) p[u] = csr[s + i + u];
    if (act) {
      unsigned int q[8];
#pragma unroll
      for (int u = 0; u < 8; ++u)
        q[u] = *(const unsigned int*)&x[(size_t)p[u].x * XPAD + d2];
#pragma unroll
      for (int u = 0; u < 8; ++u) {
        float v = __int_as_float(p[u].y);
        a0 += v * bflo(q[u]);
        a1 += v * bfhi(q[u]);
      }
    }
  }
  for (; i < n; ++i) {
    int2 p = csr[s + i];
    if (act) {
      unsigned int q = *(const unsigned int*)&x[(size_t)p.x * XPAD + d2];
      float v = __int_as_float(p.y);
      a0 += v * bflo(q);
      a1 += v * bfhi(q);
    }
  }
  if (act) {
    unsigned int o = (unsigned int)f2bf(a0) | ((unsigned int)f2bf(a1) << 16);
    *(unsigned int*)&ax[(size_t)wave * XPAD + d2] = o;
  }
}

// ---- gather SpMM, D=25(32 bf16): 4 rows per wave (16 lanes each), ILP-4, +b2 ----
__global__ __launch_bounds__(256) void spmm25_g(
    const int* __restrict__ offs, const int* __restrict__ cnt,
    const int2* __restrict__ csr, const unsigned short* __restrict__ zb,
    const float* __restrict__ b2, float* __restrict__ out) {
  int gw = (int)((blockIdx.x * blockDim.x + threadIdx.x) >> 6);
  int lane = threadIdx.x & 63;
  int sub = lane >> 4;
  int d2 = (lane & 15) * 2;
  int r = gw * 4 + sub;
  if (r >= NN) return;
  int s = offs[r];
  int n = cnt[r];
  float a0 = 0.f, a1 = 0.f;
  int i = 0;
  for (; i + 4 <= n; i += 4) {
    int2 p0 = csr[s + i + 0];
    int2 p1 = csr[s + i + 1];
    int2 p2 = csr[s + i + 2];
    int2 p3 = csr[s + i + 3];
    unsigned int q0 = *(const unsigned int*)&zb[(size_t)p0.x * ZPAD + d2];
    unsigned int q1 = *(const unsigned int*)&zb[(size_t)p1.x * ZPAD + d2];
    unsigned int q2 = *(const unsigned int*)&zb[(size_t)p2.x * ZPAD + d2];
    unsigned int q3 = *(const unsigned int*)&zb[(size_t)p3.x * ZPAD + d2];
    float v0 = __int_as_float(p0.y), v1 = __int_as_float(p1.y);
    float v2 = __int_as_float(p2.y), v3 = __int_as_float(p3.y);
    a0 += v0 * bflo(q0) + v1 * bflo(q1) + v2 * bflo(q2) + v3 * bflo(q3);
    a1 += v0 * bfhi(q0) + v1 * bfhi(q1) + v2 * bfhi(q2) + v3 * bfhi(q3);
  }
  for (; i < n; ++i) {
    int2 p = csr[s + i];
    unsigned int q = *(const unsigned int*)&zb[(size_t)p.x * ZPAD + d2];
    float v = __int_as_float(p.y);
    a0 += v * bflo(q);
    a1 += v * bfhi(q);
  }
  if (d2 < NCLS)     out[(size_t)r * NCLS + d2]     = a0 + b2[d2];
  if (d2 + 1 < NCLS) out[(size_t)r * NCLS + d2 + 1] = a1 + b2[d2 + 1];
}

// ---- Fused MLP via bf16 MFMA: z = relu(ax@W1+b1)@W2, z -> bf16[NN][32] ----
__global__ __launch_bounds__(256) void fused_mlp_mfma(
    const unsigned short* __restrict__ axg, const unsigned short* __restrict__ w1t,
    const float* __restrict__ b1, const unsigned short* __restrict__ w2t,
    unsigned short* __restrict__ zb) {
  __shared__ __align__(16) unsigned short axs[64 * 104];  // [64][96] pad->104
  __shared__ __align__(16) unsigned short hs[64 * 264];   // [64][256] pad->264
  __shared__ float b1s[DHID];
  const int tid = threadIdx.x;
  const int n0 = blockIdx.x * 64;

  for (int idx = tid; idx < 64 * 12; idx += 256) {   // 12 sh8 chunks per row
    int m = idx / 12;
    int c8 = idx - m * 12;
    int node = n0 + m;
    sh8 v = {0, 0, 0, 0, 0, 0, 0, 0};
    if (node < NN) v = *(const sh8*)&axg[(size_t)node * XPAD + c8 * 8];
    *(sh8*)&axs[m * 104 + c8 * 8] = v;
  }
  for (int i = tid; i < DHID; i += 256) b1s[i] = b1[i];
  __syncthreads();

  const int lane = tid & 63;
  const int w = tid >> 6;
  const int quad = lane >> 4;   // A/B frag: k = quad*8 + j
  const int tn = lane & 15;     // A frag: m; B frag: n; C frag: col
  const int m0 = w * 16;

  sh8 a1[4][3];
#pragma unroll
  for (int mt = 0; mt < 4; ++mt)
#pragma unroll
    for (int kc = 0; kc < 3; ++kc)
      a1[mt][kc] = *(const sh8*)&axs[(mt * 16 + tn) * 104 + kc * 32 + quad * 8];

  f4_t z0 = {0.f, 0.f, 0.f, 0.f}, z1 = {0.f, 0.f, 0.f, 0.f};

  for (int c = 0; c < 4; ++c) {
    const int cb = c * 256;
#pragma unroll
    for (int nti = 0; nti < 4; ++nti) {
      const int nt = w * 4 + nti;
      const int ng = cb + nt * 16 + tn;
      const unsigned short* wr = &w1t[(size_t)ng * XPAD + quad * 8];
      sh8 b0 = *(const sh8*)&wr[0];
      sh8 b1f = *(const sh8*)&wr[32];
      sh8 b2f = *(const sh8*)&wr[64];
      float bias = b1s[ng];
#pragma unroll
      for (int mt = 0; mt < 4; ++mt) {
        f4_t acc = {0.f, 0.f, 0.f, 0.f};
        acc = __builtin_amdgcn_mfma_f32_16x16x32_bf16(a1[mt][0], b0, acc, 0, 0, 0);
        acc = __builtin_amdgcn_mfma_f32_16x16x32_bf16(a1[mt][1], b1f, acc, 0, 0, 0);
        acc = __builtin_amdgcn_mfma_f32_16x16x32_bf16(a1[mt][2], b2f, acc, 0, 0, 0);
#pragma unroll
        for (int r = 0; r < 4; ++r) {
          float v = relu_(acc[r] + bias);          // C: col=tn, row=quad*4+r
          hs[(mt * 16 + quad * 4 + r) * 264 + nt * 16 + tn] = f2bf(v);
        }
      }
    }
    __syncthreads();
#pragma unroll
    for (int kc = 0; kc < 8; ++kc) {
      sh8 a2 = *(const sh8*)&hs[(m0 + tn) * 264 + kc * 32 + quad * 8];
      sh8 bl = *(const sh8*)&w2t[(size_t)tn * DHID + cb + kc * 32 + quad * 8];
      z0 = __builtin_amdgcn_mfma_f32_16x16x32_bf16(a2, bl, z0, 0, 0, 0);
      sh8 bh = *(const sh8*)&w2t[(size_t)(16 + tn) * DHID + cb + kc * 32 + quad * 8];
      z1 = __builtin_amdgcn_mfma_f32_16x16x32_bf16(a2, bh, z1, 0, 0, 0);
    }
    __syncthreads();
  }

#pragma unroll
  for (int r = 0; r < 4; ++r) {
    int node = n0 + m0 + quad * 4 + r;
    if (node < NN) {
      zb[(size_t)node * ZPAD + tn]      = f2bf(z0[r]);
      zb[(size_t)node * ZPAD + 16 + tn] = f2bf(z1[r]);
    }
  }
}

extern "C" void kernel_launch(void* const* d_in, const int* in_sizes, int n_in,
                              void* d_out, int out_size, void* d_ws, size_t ws_size,
                              hipStream_t stream) {
  const float* feature = (const float*)d_in[0];
  const float* conv_w  = (const float*)d_in[1];
  const float* conv_b  = (const float*)d_in[2];
  const float* W1      = (const float*)d_in[3];
  const float* b1      = (const float*)d_in[4];
  const float* W2      = (const float*)d_in[5];
  const float* b2      = (const float*)d_in[6];
  const float* adj     = (const float*)d_in[7];
  const int*   erow    = (const int*)d_in[8];
  const int*   ecol    = (const int*)d_in[9];
  float* out = (float*)d_out;

  char* B = (char*)d_ws;
  size_t o = 0;
  auto alloc = [&](size_t bytes, size_t align) -> void* {
    o = (o + align - 1) & ~(align - 1);
    void* p = B + o;
    o += bytes;
    return p;
  };
  unsigned short* x    = (unsigned short*)alloc((size_t)NN * XPAD * 2, 16);
  unsigned short* ax   = (unsigned short*)alloc((size_t)NN * XPAD * 2, 16);
  unsigned short* zb   = (unsigned short*)alloc((size_t)NN * ZPAD * 2, 16);
  int*   counts  = (int*)alloc((size_t)NN * 4, 16);
  int*   offs    = (int*)alloc((size_t)NN * 4, 16);
  int*   gcur    = (int*)alloc((size_t)NBK * 16 * 4, 64);  // line-padded cursors
  int*   gbk     = (int*)alloc((size_t)NBK * 16 * 4, 64);  // line-padded totals
  int*   bbase   = (int*)alloc((size_t)(NBK + 1) * 4, 16); // bucket bases
  unsigned short* w1t = (unsigned short*)alloc((size_t)DHID * XPAD * 2, 16);
  unsigned short* w2t = (unsigned short*)alloc((size_t)32 * DHID * 2, 16);
  int2*  tmp     = (int2*)alloc((size_t)EE * 8, 16);  // bucket-major
  int2*  csr     = (int2*)alloc((size_t)EE * 8, 16);  // row-sorted

  // 1) x = relu(conv_sum(feature)) -> bf16 [NN][96]; weight prep
  conv_relu_k<<<8192, 256, 0, stream>>>(feature, conv_w, conv_b, x);
  w1t_k<<<(DHID * XPAD + 255) / 256, 256, 0, stream>>>(W1, w1t);
  w2t_k<<<(32 * DHID + 255) / 256, 256, 0, stream>>>(W2, w2t);
  // 2) CSR build: bucket hist -> bucket scan -> partition -> fine scatter(+offs)
  zero_int_k<<<32, 256, 0, stream>>>(gbk, NBK * 16);
  bucket_hist_k<<<(EE + CHUNK - 1) / CHUNK, 256, 0, stream>>>(erow, gbk);
  scan_buckets_k<<<1, 512, 0, stream>>>(gbk, bbase, gcur);
  partition_k<<<(EE + CHUNK - 1) / CHUNK, 256, 0, stream>>>(adj, erow, ecol, gcur, tmp);
  fine_scatter2_k<<<NBK, 256, 0, stream>>>(bbase, tmp, csr, offs, counts);
  // 3) ax = A @ x (gather, bf16 rows, ILP-8)
  spmm83_g<<<(NN + 3) / 4, 256, 0, stream>>>(offs, counts, csr, x, ax);
  // 4) z = relu(ax @ W1 + b1) @ W2 via bf16 MFMA -> bf16 [NN][32]
  fused_mlp_mfma<<<(NN + 63) / 64, 256, 0, stream>>>(ax, w1t, b1, w2t, zb);
  // 5) out = A @ z + b2 (gather, 1 line per edge, ILP-4)
  spmm25_g<<<(NN + 15) / 16, 256, 0, stream>>>(offs, counts, csr, zb, b2, out);
}

// Round 10
// 478.983 us; speedup vs baseline: 6.2299x; 1.0525x over previous
//
#include <hip/hip_runtime.h>

#define NN   100000
#define EE   3200000
#define DIN  83
#define DHID 1024
#define NCLS 25
#define XPAD 96    // x/ax bf16 row padding (192 B = 3 cache lines)
#define ZPAD 32    // z bf16 row padding (64 B = 1 cache line)

#define NBK     391   // buckets of 256 rows (row >> 8)
#define CHUNK   8192  // edges per partition block

typedef __attribute__((__ext_vector_type__(8))) short sh8;
typedef __attribute__((__ext_vector_type__(4))) float f4_t;

static __device__ __forceinline__ float relu_(float v) { return v > 0.f ? v : 0.f; }

// f32 -> bf16 (RNE)
static __device__ __forceinline__ unsigned short f2bf(float f) {
  unsigned int u = __float_as_uint(f);
  unsigned int r = u + 0x7FFFu + ((u >> 16) & 1u);
  return (unsigned short)(r >> 16);
}
// packed bf16 pair -> two f32
static __device__ __forceinline__ float bflo(unsigned int q) {
  return __uint_as_float(q << 16);
}
static __device__ __forceinline__ float bfhi(unsigned int q) {
  return __uint_as_float(q & 0xFFFF0000u);
}

// K1: Conv1d(1->4,k5,p2) + channel-sum + bias + relu -> bf16 x[NN][96]
__global__ void conv_relu_k(const float* __restrict__ feature,
                            const float* __restrict__ conv_w,
                            const float* __restrict__ conv_b,
                            unsigned short* __restrict__ x) {
  float ws0 = conv_w[0] + conv_w[5] + conv_w[10] + conv_w[15];
  float ws1 = conv_w[1] + conv_w[6] + conv_w[11] + conv_w[16];
  float ws2 = conv_w[2] + conv_w[7] + conv_w[12] + conv_w[17];
  float ws3 = conv_w[3] + conv_w[8] + conv_w[13] + conv_w[18];
  float ws4 = conv_w[4] + conv_w[9] + conv_w[14] + conv_w[19];
  float bs  = conv_b[0] + conv_b[1] + conv_b[2] + conv_b[3];
  const int total = NN * XPAD;
  for (int idx = blockIdx.x * blockDim.x + threadIdx.x; idx < total;
       idx += gridDim.x * blockDim.x) {
    int n = idx / XPAD;
    int i = idx - n * XPAD;
    unsigned short o = 0;
    if (i < DIN) {
      const float* f = feature + (size_t)n * DIN;
      float acc = bs;
      if (i >= 2)      acc += ws0 * f[i - 2];
      if (i >= 1)      acc += ws1 * f[i - 1];
      acc += ws2 * f[i];
      if (i + 1 < DIN) acc += ws3 * f[i + 1];
      if (i + 2 < DIN) acc += ws4 * f[i + 2];
      o = f2bf(relu_(acc));
    }
    x[idx] = o;
  }
}

// Combined prep: w1t transpose, w2t transpose, gbk zero (grid covers max range)
__global__ void prep_k(const float* __restrict__ W1, unsigned short* __restrict__ w1t,
                       const float* __restrict__ W2, unsigned short* __restrict__ w2t,
                       int* __restrict__ gbk) {
  int idx = blockIdx.x * blockDim.x + threadIdx.x;
  if (idx < DHID * XPAD) {            // w1t[1024][96], K zero-padded
    int k = idx / DHID;
    int n = idx - k * DHID;
    float v = (k < DIN) ? W1[k * DHID + n] : 0.f;
    w1t[n * XPAD + k] = f2bf(v);
  }
  if (idx < 32 * DHID) {              // w2t[32][1024], N zero-padded
    int k = idx / 32;
    int n = idx - k * 32;
    float v = (n < NCLS) ? W2[k * NCLS + n] : 0.f;
    w2t[n * DHID + k] = f2bf(v);
  }
  if (idx < NBK * 16) gbk[idx] = 0;
}

// ---- CSR build (bucket-hierarchical) ----

__global__ __launch_bounds__(256) void bucket_hist_k(
    const int* __restrict__ row, int* __restrict__ gbk) {
  __shared__ int cnt[NBK];
  const int tid = threadIdx.x;
  for (int b = tid; b < NBK; b += 256) cnt[b] = 0;
  __syncthreads();
  const int cb = blockIdx.x * CHUNK;
  const int csize = (cb + CHUNK <= EE) ? CHUNK : (EE - cb);
  for (int i = tid; i < csize; i += 256)
    atomicAdd(&cnt[row[cb + i] >> 8], 1);
  __syncthreads();
  for (int b = tid; b < NBK; b += 256)
    if (cnt[b]) atomicAdd(&gbk[b * 16], cnt[b]);
}

__global__ void scan_buckets_k(const int* __restrict__ gbk,
                               int* __restrict__ bbase, int* __restrict__ gcur) {
  __shared__ int sd[512];
  int t = threadIdx.x;
  int v = (t < NBK) ? gbk[t * 16] : 0;
  sd[t] = v;
  __syncthreads();
  for (int off = 1; off < 512; off <<= 1) {
    int add = (t >= off) ? sd[t - off] : 0;
    __syncthreads();
    sd[t] += add;
    __syncthreads();
  }
  if (t < NBK) {
    int excl = sd[t] - v;
    bbase[t] = excl;
    gcur[t * 16] = excl;   // line-padded cursor
  }
  if (t == 0) bbase[NBK] = EE;
}

// Pass 1: partition edges into 391 buckets (row>>8), bucket-major tmp.
__global__ __launch_bounds__(256) void partition_k(
    const float* __restrict__ vals, const int* __restrict__ row,
    const int* __restrict__ col, int* __restrict__ gcur,
    int2* __restrict__ tmp) {
  __shared__ int cnt[NBK];
  __shared__ int sc[512];       // scan scratch
  __shared__ int es[NBK + 1];   // exclusive start per bucket (+end)
  __shared__ int lcur[NBK];
  __shared__ int gbase[NBK];
  __shared__ int2 staged[CHUNK];
  const int tid = threadIdx.x;
  const int cb = blockIdx.x * CHUNK;
  const int csize = (cb + CHUNK <= EE) ? CHUNK : (EE - cb);

  for (int b = tid; b < NBK; b += 256) cnt[b] = 0;
  __syncthreads();
  for (int i = tid; i < csize; i += 256)
    atomicAdd(&cnt[row[cb + i] >> 8], 1);
  __syncthreads();
  sc[tid]       = (tid < NBK) ? cnt[tid] : 0;
  sc[tid + 256] = (tid + 256 < NBK) ? cnt[tid + 256] : 0;
  __syncthreads();
  for (int off = 1; off < 512; off <<= 1) {
    int a0 = (tid >= off) ? sc[tid - off] : 0;
    int a1 = (tid + 256 >= off) ? sc[tid + 256 - off] : 0;
    __syncthreads();
    sc[tid] += a0;
    sc[tid + 256] += a1;
    __syncthreads();
  }
  for (int b = tid; b < NBK; b += 256) {
    int e = sc[b] - cnt[b];   // exclusive
    es[b] = e;
    lcur[b] = e;
  }
  if (tid == 0) es[NBK] = csize;
  __syncthreads();
  for (int b = tid; b < NBK; b += 256)
    gbase[b] = cnt[b] ? atomicAdd(&gcur[b * 16], cnt[b]) : 0;
  __syncthreads();
  for (int i = tid; i < csize; i += 256) {
    int r = row[cb + i];
    int lpos = atomicAdd(&lcur[r >> 8], 1);
    staged[lpos] = make_int2(col[cb + i] | ((r & 255) << 17),
                             __float_as_int(vals[cb + i]));
  }
  __syncthreads();
  // flush: wave w copies buckets w, w+4, ... as contiguous runs
  {
    const int w = tid >> 6;
    const int lane = tid & 63;
    for (int b = w; b < NBK; b += 4) {
      int st = es[b], en = es[b + 1];
      int gb = gbase[b];
      for (int j = st + lane; j < en; j += 64)
        tmp[gb + (j - st)] = staged[j];
    }
  }
}

// Pass 2: per-bucket fine scatter + per-row offset derivation (all in LDS).
__global__ __launch_bounds__(256) void fine_scatter2_k(
    const int* __restrict__ bbase, const int2* __restrict__ tmp,
    int2* __restrict__ csr, int* __restrict__ offs, int* __restrict__ counts) {
  __shared__ int cnt[256];
  __shared__ int sd[256];
  __shared__ int lcur[256];
  const int tid = threadIdx.x;
  const int b = blockIdx.x;
  const int r0 = b * 256;
  const int gstart = bbase[b];
  const int nedge = bbase[b + 1] - gstart;
  cnt[tid] = 0;
  __syncthreads();
  for (int i = tid; i < nedge; i += 256)
    atomicAdd(&cnt[((unsigned)tmp[gstart + i].x) >> 17], 1);
  __syncthreads();
  int v = cnt[tid];
  sd[tid] = v;
  __syncthreads();
  for (int off = 1; off < 256; off <<= 1) {
    int add = (tid >= off) ? sd[tid - off] : 0;
    __syncthreads();
    sd[tid] += add;
    __syncthreads();
  }
  int excl = gstart + sd[tid] - v;
  int r = r0 + tid;
  if (r < NN) {
    offs[r] = excl;
    counts[r] = v;
  }
  lcur[tid] = excl;
  __syncthreads();
  for (int i = tid; i < nedge; i += 256) {
    int2 p = tmp[gstart + i];
    int rl = ((unsigned)p.x) >> 17;
    int pos = atomicAdd(&lcur[rl], 1);
    csr[pos] = make_int2(p.x & 0x1FFFF, p.y);
  }
}

// ---- gather SpMM, D=83(96 bf16): one wave per row, ILP-8, scalar edge loads ----
__global__ __launch_bounds__(256) void spmm83_g(
    const int* __restrict__ offs, const int* __restrict__ cnt,
    const int2* __restrict__ csr, const unsigned short* __restrict__ x,
    unsigned short* __restrict__ ax) {
  int wave = (int)((blockIdx.x * blockDim.x + threadIdx.x) >> 6);
  int lane = threadIdx.x & 63;
  if (wave >= NN) return;
  int s = __builtin_amdgcn_readfirstlane(offs[wave]);   // wave-uniform -> SGPR
  int n = __builtin_amdgcn_readfirstlane(cnt[wave]);
  const bool act = lane < 48;         // 48 lanes x short2 = 96 dims
  const int d2 = lane * 2;
  float a0 = 0.f, a1 = 0.f;
  int i = 0;
  for (; i + 8 <= n; i += 8) {
    int2 p[8];
#pragma unroll
    for (int u = 0; u < 8; ++u) p[u] = csr[s + i + u];
    if (act) {
      unsigned int q[8];
#pragma unroll
      for (int u = 0; u < 8; ++u)
        q[u] = *(const unsigned int*)&x[(size_t)p[u].x * XPAD + d2];
#pragma unroll
      for (int u = 0; u < 8; ++u) {
        float v = __int_as_float(p[u].y);
        a0 += v * bflo(q[u]);
        a1 += v * bfhi(q[u]);
      }
    }
  }
  for (; i < n; ++i) {
    int2 p = csr[s + i];
    if (act) {
      unsigned int q = *(const unsigned int*)&x[(size_t)p.x * XPAD + d2];
      float v = __int_as_float(p.y);
      a0 += v * bflo(q);
      a1 += v * bfhi(q);
    }
  }
  if (act) {
    unsigned int o = (unsigned int)f2bf(a0) | ((unsigned int)f2bf(a1) << 16);
    *(unsigned int*)&ax[(size_t)wave * XPAD + d2] = o;
  }
}

// ---- gather SpMM, D=25(32 bf16): 4 rows per wave (16 lanes each), ILP-4, +b2 ----
__global__ __launch_bounds__(256) void spmm25_g(
    const int* __restrict__ offs, const int* __restrict__ cnt,
    const int2* __restrict__ csr, const unsigned short* __restrict__ zb,
    const float* __restrict__ b2, float* __restrict__ out) {
  int gw = (int)((blockIdx.x * blockDim.x + threadIdx.x) >> 6);
  int lane = threadIdx.x & 63;
  int sub = lane >> 4;
  int d2 = (lane & 15) * 2;
  int r = gw * 4 + sub;
  if (r >= NN) return;
  int s = offs[r];
  int n = cnt[r];
  float a0 = 0.f, a1 = 0.f;
  int i = 0;
  for (; i + 4 <= n; i += 4) {
    int2 p0 = csr[s + i + 0];
    int2 p1 = csr[s + i + 1];
    int2 p2 = csr[s + i + 2];
    int2 p3 = csr[s + i + 3];
    unsigned int q0 = *(const unsigned int*)&zb[(size_t)p0.x * ZPAD + d2];
    unsigned int q1 = *(const unsigned int*)&zb[(size_t)p1.x * ZPAD + d2];
    unsigned int q2 = *(const unsigned int*)&zb[(size_t)p2.x * ZPAD + d2];
    unsigned int q3 = *(const unsigned int*)&zb[(size_t)p3.x * ZPAD + d2];
    float v0 = __int_as_float(p0.y), v1 = __int_as_float(p1.y);
    float v2 = __int_as_float(p2.y), v3 = __int_as_float(p3.y);
    a0 += v0 * bflo(q0) + v1 * bflo(q1) + v2 * bflo(q2) + v3 * bflo(q3);
    a1 += v0 * bfhi(q0) + v1 * bfhi(q1) + v2 * bfhi(q2) + v3 * bfhi(q3);
  }
  for (; i < n; ++i) {
    int2 p = csr[s + i];
    unsigned int q = *(const unsigned int*)&zb[(size_t)p.x * ZPAD + d2];
    float v = __int_as_float(p.y);
    a0 += v * bflo(q);
    a1 += v * bfhi(q);
  }
  if (d2 < NCLS)     out[(size_t)r * NCLS + d2]     = a0 + b2[d2];
  if (d2 + 1 < NCLS) out[(size_t)r * NCLS + d2 + 1] = a1 + b2[d2 + 1];
}

// ---- Fused MLP via bf16 MFMA: z = relu(ax@W1+b1)@W2, z -> bf16[NN][32] ----
// Block = 128 nodes, 4 waves, hidden chunked x128 (8 chunks). Each wave holds
// A-frags for ALL 8 m-tiles; per chunk wave covers 2 n-tiles (B-frag feeds
// 8 MFMAs). GEMM2: wave owns m-tiles {w, w+4}. LDS = 64 KB -> 2 blocks/CU.
__global__ __launch_bounds__(256) void fused_mlp_mfma(
    const unsigned short* __restrict__ axg, const unsigned short* __restrict__ w1t,
    const float* __restrict__ b1, const unsigned short* __restrict__ w2t,
    unsigned short* __restrict__ zb) {
  __shared__ __align__(16) unsigned short axs[128 * 104];  // 26.6 KB
  __shared__ __align__(16) unsigned short hs[128 * 136];   // 34.8 KB (chunk 128)
  __shared__ float b1s[DHID];                              // 4 KB
  const int tid = threadIdx.x;
  const int n0 = blockIdx.x * 128;

  for (int idx = tid; idx < 128 * 12; idx += 256) {   // 12 sh8 chunks per row
    int m = idx / 12;
    int c8 = idx - m * 12;
    int node = n0 + m;
    sh8 v = {0, 0, 0, 0, 0, 0, 0, 0};
    if (node < NN) v = *(const sh8*)&axg[(size_t)node * XPAD + c8 * 8];
    *(sh8*)&axs[m * 104 + c8 * 8] = v;
  }
  for (int i = tid; i < DHID; i += 256) b1s[i] = b1[i];
  __syncthreads();

  const int lane = tid & 63;
  const int w = tid >> 6;
  const int quad = lane >> 4;   // A/B frag: k = quad*8 + j
  const int tn = lane & 15;     // A frag: m; B frag: n; C frag: col
  const int mta = w;            // GEMM2 m-tile 1
  const int mtb = w + 4;        // GEMM2 m-tile 2

  sh8 a1[8][3];
#pragma unroll
  for (int mt = 0; mt < 8; ++mt)
#pragma unroll
    for (int kc = 0; kc < 3; ++kc)
      a1[mt][kc] = *(const sh8*)&axs[(mt * 16 + tn) * 104 + kc * 32 + quad * 8];

  f4_t za0 = {0.f, 0.f, 0.f, 0.f}, za1 = {0.f, 0.f, 0.f, 0.f};
  f4_t zb0 = {0.f, 0.f, 0.f, 0.f}, zb1 = {0.f, 0.f, 0.f, 0.f};

  for (int c = 0; c < 8; ++c) {
    const int cb = c * 128;
    // GEMM1: wave w -> n-tiles w*2, w*2+1 ; all 8 m-tiles
#pragma unroll
    for (int nti = 0; nti < 2; ++nti) {
      const int nt = w * 2 + nti;
      const int ng = cb + nt * 16 + tn;
      const unsigned short* wr = &w1t[(size_t)ng * XPAD + quad * 8];
      sh8 b0 = *(const sh8*)&wr[0];
      sh8 b1f = *(const sh8*)&wr[32];
      sh8 b2f = *(const sh8*)&wr[64];
      float bias = b1s[ng];
#pragma unroll
      for (int mt = 0; mt < 8; ++mt) {
        f4_t acc = {0.f, 0.f, 0.f, 0.f};
        acc = __builtin_amdgcn_mfma_f32_16x16x32_bf16(a1[mt][0], b0, acc, 0, 0, 0);
        acc = __builtin_amdgcn_mfma_f32_16x16x32_bf16(a1[mt][1], b1f, acc, 0, 0, 0);
        acc = __builtin_amdgcn_mfma_f32_16x16x32_bf16(a1[mt][2], b2f, acc, 0, 0, 0);
#pragma unroll
        for (int r = 0; r < 4; ++r) {
          float v = relu_(acc[r] + bias);          // C: col=tn, row=quad*4+r
          hs[(mt * 16 + quad * 4 + r) * 136 + nt * 16 + tn] = f2bf(v);
        }
      }
    }
    __syncthreads();
    // GEMM2: z[16,32] += h_chunk[16,128] @ W2[cb..cb+127, :]; wave -> m-tiles w, w+4
#pragma unroll
    for (int kc = 0; kc < 4; ++kc) {
      sh8 bl = *(const sh8*)&w2t[(size_t)tn * DHID + cb + kc * 32 + quad * 8];
      sh8 bh = *(const sh8*)&w2t[(size_t)(16 + tn) * DHID + cb + kc * 32 + quad * 8];
      sh8 aa = *(const sh8*)&hs[(mta * 16 + tn) * 136 + kc * 32 + quad * 8];
      za0 = __builtin_amdgcn_mfma_f32_16x16x32_bf16(aa, bl, za0, 0, 0, 0);
      za1 = __builtin_amdgcn_mfma_f32_16x16x32_bf16(aa, bh, za1, 0, 0, 0);
      sh8 ab = *(const sh8*)&hs[(mtb * 16 + tn) * 136 + kc * 32 + quad * 8];
      zb0 = __builtin_amdgcn_mfma_f32_16x16x32_bf16(ab, bl, zb0, 0, 0, 0);
      zb1 = __builtin_amdgcn_mfma_f32_16x16x32_bf16(ab, bh, zb1, 0, 0, 0);
    }
    __syncthreads();
  }

#pragma unroll
  for (int r = 0; r < 4; ++r) {
    int na = n0 + mta * 16 + quad * 4 + r;
    if (na < NN) {
      zb[(size_t)na * ZPAD + tn]      = f2bf(za0[r]);
      zb[(size_t)na * ZPAD + 16 + tn] = f2bf(za1[r]);
    }
    int nb = n0 + mtb * 16 + quad * 4 + r;
    if (nb < NN) {
      zb[(size_t)nb * ZPAD + tn]      = f2bf(zb0[r]);
      zb[(size_t)nb * ZPAD + 16 + tn] = f2bf(zb1[r]);
    }
  }
}

extern "C" void kernel_launch(void* const* d_in, const int* in_sizes, int n_in,
                              void* d_out, int out_size, void* d_ws, size_t ws_size,
                              hipStream_t stream) {
  const float* feature = (const float*)d_in[0];
  const float* conv_w  = (const float*)d_in[1];
  const float* conv_b  = (const float*)d_in[2];
  const float* W1      = (const float*)d_in[3];
  const float* b1      = (const float*)d_in[4];
  const float* W2      = (const float*)d_in[5];
  const float* b2      = (const float*)d_in[6];
  const float* adj     = (const float*)d_in[7];
  const int*   erow    = (const int*)d_in[8];
  const int*   ecol    = (const int*)d_in[9];
  float* out = (float*)d_out;

  char* B = (char*)d_ws;
  size_t o = 0;
  auto alloc = [&](size_t bytes, size_t align) -> void* {
    o = (o + align - 1) & ~(align - 1);
    void* p = B + o;
    o += bytes;
    return p;
  };
  unsigned short* x    = (unsigned short*)alloc((size_t)NN * XPAD * 2, 16);
  unsigned short* ax   = (unsigned short*)alloc((size_t)NN * XPAD * 2, 16);
  unsigned short* zb   = (unsigned short*)alloc((size_t)NN * ZPAD * 2, 16);
  int*   counts  = (int*)alloc((size_t)NN * 4, 16);
  int*   offs    = (int*)alloc((size_t)NN * 4, 16);
  int*   gcur    = (int*)alloc((size_t)NBK * 16 * 4, 64);  // line-padded cursors
  int*   gbk     = (int*)alloc((size_t)NBK * 16 * 4, 64);  // line-padded totals
  int*   bbase   = (int*)alloc((size_t)(NBK + 1) * 4, 16); // bucket bases
  unsigned short* w1t = (unsigned short*)alloc((size_t)DHID * XPAD * 2, 16);
  unsigned short* w2t = (unsigned short*)alloc((size_t)32 * DHID * 2, 16);
  int2*  tmp     = (int2*)alloc((size_t)EE * 8, 16);  // bucket-major
  int2*  csr     = (int2*)alloc((size_t)EE * 8, 16);  // row-sorted

  // 1) x = relu(conv_sum(feature)); weight transposes + gbk zero (merged)
  conv_relu_k<<<8192, 256, 0, stream>>>(feature, conv_w, conv_b, x);
  prep_k<<<(DHID * XPAD + 255) / 256, 256, 0, stream>>>(W1, w1t, W2, w2t, gbk);
  // 2) CSR build: bucket hist -> bucket scan -> partition -> fine scatter(+offs)
  bucket_hist_k<<<(EE + CHUNK - 1) / CHUNK, 256, 0, stream>>>(erow, gbk);
  scan_buckets_k<<<1, 512, 0, stream>>>(gbk, bbase, gcur);
  partition_k<<<(EE + CHUNK - 1) / CHUNK, 256, 0, stream>>>(adj, erow, ecol, gcur, tmp);
  fine_scatter2_k<<<NBK, 256, 0, stream>>>(bbase, tmp, csr, offs, counts);
  // 3) ax = A @ x (gather, bf16 rows, ILP-8, scalar edge loads)
  spmm83_g<<<(NN + 3) / 4, 256, 0, stream>>>(offs, counts, csr, x, ax);
  // 4) z = relu(ax @ W1 + b1) @ W2 via bf16 MFMA (128-node tiles) -> bf16 [NN][32]
  fused_mlp_mfma<<<(NN + 127) / 128, 256, 0, stream>>>(ax, w1t, b1, w2t, zb);
  // 5) out = A @ z + b2 (gather, 1 line per edge, ILP-4)
  spmm25_g<<<(NN + 15) / 16, 256, 0, stream>>>(offs, counts, csr, zb, b2, out);
}

// Round 11
// 472.148 us; speedup vs baseline: 6.3200x; 1.0145x over previous
//
#include <hip/hip_runtime.h>

#define NN   100000
#define EE   3200000
#define DIN  83
#define DHID 1024
#define NCLS 25
#define XPAD 96    // x/ax bf16 row padding (192 B = 3 cache lines)
#define ZPAD 32    // z bf16 row padding (64 B = 1 cache line)

#define NBK     391   // buckets of 256 rows (row >> 8)
#define CHUNK   8192  // edges per partition block

typedef __attribute__((__ext_vector_type__(8))) short sh8;
typedef __attribute__((__ext_vector_type__(4))) float f4_t;

static __device__ __forceinline__ float relu_(float v) { return v > 0.f ? v : 0.f; }

// f32 -> bf16 (RNE)
static __device__ __forceinline__ unsigned short f2bf(float f) {
  unsigned int u = __float_as_uint(f);
  unsigned int r = u + 0x7FFFu + ((u >> 16) & 1u);
  return (unsigned short)(r >> 16);
}
// packed bf16 pair -> two f32
static __device__ __forceinline__ float bflo(unsigned int q) {
  return __uint_as_float(q << 16);
}
static __device__ __forceinline__ float bfhi(unsigned int q) {
  return __uint_as_float(q & 0xFFFF0000u);
}

// K1: Conv1d(1->4,k5,p2) + channel-sum + bias + relu -> bf16 x[NN][96]
__global__ void conv_relu_k(const float* __restrict__ feature,
                            const float* __restrict__ conv_w,
                            const float* __restrict__ conv_b,
                            unsigned short* __restrict__ x) {
  float ws0 = conv_w[0] + conv_w[5] + conv_w[10] + conv_w[15];
  float ws1 = conv_w[1] + conv_w[6] + conv_w[11] + conv_w[16];
  float ws2 = conv_w[2] + conv_w[7] + conv_w[12] + conv_w[17];
  float ws3 = conv_w[3] + conv_w[8] + conv_w[13] + conv_w[18];
  float ws4 = conv_w[4] + conv_w[9] + conv_w[14] + conv_w[19];
  float bs  = conv_b[0] + conv_b[1] + conv_b[2] + conv_b[3];
  const int total = NN * XPAD;
  for (int idx = blockIdx.x * blockDim.x + threadIdx.x; idx < total;
       idx += gridDim.x * blockDim.x) {
    int n = idx / XPAD;
    int i = idx - n * XPAD;
    unsigned short o = 0;
    if (i < DIN) {
      const float* f = feature + (size_t)n * DIN;
      float acc = bs;
      if (i >= 2)      acc += ws0 * f[i - 2];
      if (i >= 1)      acc += ws1 * f[i - 1];
      acc += ws2 * f[i];
      if (i + 1 < DIN) acc += ws3 * f[i + 1];
      if (i + 2 < DIN) acc += ws4 * f[i + 2];
      o = f2bf(relu_(acc));
    }
    x[idx] = o;
  }
}

// Combined prep: w1t transpose, w2t transpose, gbk zero
__global__ void prep_k(const float* __restrict__ W1, unsigned short* __restrict__ w1t,
                       const float* __restrict__ W2, unsigned short* __restrict__ w2t,
                       int* __restrict__ gbk) {
  int idx = blockIdx.x * blockDim.x + threadIdx.x;
  if (idx < DHID * XPAD) {            // w1t[1024][96], K zero-padded
    int k = idx / DHID;
    int n = idx - k * DHID;
    float v = (k < DIN) ? W1[k * DHID + n] : 0.f;
    w1t[n * XPAD + k] = f2bf(v);
  }
  if (idx < 32 * DHID) {              // w2t[32][1024], N zero-padded
    int k = idx / 32;
    int n = idx - k * 32;
    float v = (n < NCLS) ? W2[k * NCLS + n] : 0.f;
    w2t[n * DHID + k] = f2bf(v);
  }
  if (idx < NBK * 16) gbk[idx] = 0;
}

// ---- CSR build (bucket-hierarchical) ----

__global__ __launch_bounds__(512) void bucket_hist_k(
    const int* __restrict__ row, int* __restrict__ gbk) {
  __shared__ int cnt[NBK];
  const int tid = threadIdx.x;
  for (int b = tid; b < NBK; b += 512) cnt[b] = 0;
  __syncthreads();
  const int cb = blockIdx.x * CHUNK;
  const int csize = (cb + CHUNK <= EE) ? CHUNK : (EE - cb);
  for (int i = tid; i < csize; i += 512)
    atomicAdd(&cnt[row[cb + i] >> 8], 1);
  __syncthreads();
  for (int b = tid; b < NBK; b += 512)
    if (cnt[b]) atomicAdd(&gbk[b * 16], cnt[b]);
}

__global__ void scan_buckets_k(const int* __restrict__ gbk,
                               int* __restrict__ bbase, int* __restrict__ gcur) {
  __shared__ int sd[512];
  int t = threadIdx.x;
  int v = (t < NBK) ? gbk[t * 16] : 0;
  sd[t] = v;
  __syncthreads();
  for (int off = 1; off < 512; off <<= 1) {
    int add = (t >= off) ? sd[t - off] : 0;
    __syncthreads();
    sd[t] += add;
    __syncthreads();
  }
  if (t < NBK) {
    int excl = sd[t] - v;
    bbase[t] = excl;
    gcur[t * 16] = excl;   // line-padded cursor
  }
  if (t == 0) bbase[NBK] = EE;
}

// Pass 1: partition into bucket-major tmp via direct reserved-range scatter.
// Per-block: LDS hist -> one global reservation atomic per bucket -> per-edge
// LDS cursor atomic gives FINAL global slot (block-exclusive ~21-edge runs,
// L2 write-combines ~8 edges/line). No staged LDS, no scan, no flush pass.
__global__ __launch_bounds__(256) void partition_k(
    const float* __restrict__ vals, const int* __restrict__ row,
    const int* __restrict__ col, int* __restrict__ gcur,
    int2* __restrict__ tmp) {
  __shared__ int cnt[NBK];
  __shared__ int lcur[NBK];
  const int tid = threadIdx.x;
  const int cb = blockIdx.x * CHUNK;
  const int csize = (cb + CHUNK <= EE) ? CHUNK : (EE - cb);

  for (int b = tid; b < NBK; b += 256) cnt[b] = 0;
  __syncthreads();
  for (int i = tid; i < csize; i += 256)
    atomicAdd(&cnt[row[cb + i] >> 8], 1);
  __syncthreads();
  for (int b = tid; b < NBK; b += 256)
    lcur[b] = cnt[b] ? atomicAdd(&gcur[b * 16], cnt[b]) : 0;
  __syncthreads();
  for (int i = tid; i < csize; i += 256) {
    int r = row[cb + i];
    int pos = atomicAdd(&lcur[r >> 8], 1);
    tmp[pos] = make_int2(col[cb + i] | ((r & 255) << 17),
                         __float_as_int(vals[cb + i]));
  }
}

// Pass 2: per-bucket fine scatter + per-row offset derivation (512 threads).
__global__ __launch_bounds__(512) void fine_scatter2_k(
    const int* __restrict__ bbase, const int2* __restrict__ tmp,
    int2* __restrict__ csr, int* __restrict__ offs, int* __restrict__ counts) {
  __shared__ int cnt[256];
  __shared__ int sd[256];
  __shared__ int lcur[256];
  const int tid = threadIdx.x;
  const int b = blockIdx.x;
  const int r0 = b * 256;
  const int gstart = bbase[b];
  const int nedge = bbase[b + 1] - gstart;
  if (tid < 256) cnt[tid] = 0;
  __syncthreads();
  // Phase A: per-row histogram (LDS atomics)
  for (int i = tid; i < nedge; i += 512)
    atomicAdd(&cnt[((unsigned)tmp[gstart + i].x) >> 17], 1);
  __syncthreads();
  // Phase B: exclusive scan of 256 row counts (first 256 threads)
  int v = 0;
  if (tid < 256) { v = cnt[tid]; sd[tid] = v; }
  __syncthreads();
  for (int off = 1; off < 256; off <<= 1) {
    int add = (tid >= off && tid < 256) ? sd[tid - off] : 0;
    __syncthreads();
    if (tid < 256) sd[tid] += add;
    __syncthreads();
  }
  if (tid < 256) {
    int excl = gstart + sd[tid] - v;
    int r = r0 + tid;
    if (r < NN) {
      offs[r] = excl;
      counts[r] = v;
    }
    lcur[tid] = excl;
  }
  __syncthreads();
  // Phase C: scatter within the bucket's ~128KB window (L2-local)
  for (int i = tid; i < nedge; i += 512) {
    int2 p = tmp[gstart + i];
    int rl = ((unsigned)p.x) >> 17;
    int pos = atomicAdd(&lcur[rl], 1);
    csr[pos] = make_int2(p.x & 0x1FFFF, p.y);
  }
}

// ---- gather SpMM, D=83(96 bf16): one wave per row, ILP-8, scalar edge loads ----
__global__ __launch_bounds__(256) void spmm83_g(
    const int* __restrict__ offs, const int* __restrict__ cnt,
    const int2* __restrict__ csr, const unsigned short* __restrict__ x,
    unsigned short* __restrict__ ax) {
  int wave = (int)((blockIdx.x * blockDim.x + threadIdx.x) >> 6);
  int lane = threadIdx.x & 63;
  if (wave >= NN) return;
  int s = __builtin_amdgcn_readfirstlane(offs[wave]);   // wave-uniform -> SGPR
  int n = __builtin_amdgcn_readfirstlane(cnt[wave]);
  const bool act = lane < 48;         // 48 lanes x short2 = 96 dims
  const int d2 = lane * 2;
  float a0 = 0.f, a1 = 0.f;
  int i = 0;
  for (; i + 8 <= n; i += 8) {
    int2 p[8];
#pragma unroll
    for (int u = 0; u < 8; ++u) p[u] = csr[s + i + u];
    if (act) {
      unsigned int q[8];
#pragma unroll
      for (int u = 0; u < 8; ++u)
        q[u] = *(const unsigned int*)&x[(size_t)p[u].x * XPAD + d2];
#pragma unroll
      for (int u = 0; u < 8; ++u) {
        float v = __int_as_float(p[u].y);
        a0 += v * bflo(q[u]);
        a1 += v * bfhi(q[u]);
      }
    }
  }
  for (; i < n; ++i) {
    int2 p = csr[s + i];
    if (act) {
      unsigned int q = *(const unsigned int*)&x[(size_t)p.x * XPAD + d2];
      float v = __int_as_float(p.y);
      a0 += v * bflo(q);
      a1 += v * bfhi(q);
    }
  }
  if (act) {
    unsigned int o = (unsigned int)f2bf(a0) | ((unsigned int)f2bf(a1) << 16);
    *(unsigned int*)&ax[(size_t)wave * XPAD + d2] = o;
  }
}

// ---- gather SpMM, D=25(32 bf16): 4 rows per wave (16 lanes each), ILP-4, +b2 ----
__global__ __launch_bounds__(256) void spmm25_g(
    const int* __restrict__ offs, const int* __restrict__ cnt,
    const int2* __restrict__ csr, const unsigned short* __restrict__ zb,
    const float* __restrict__ b2, float* __restrict__ out) {
  int gw = (int)((blockIdx.x * blockDim.x + threadIdx.x) >> 6);
  int lane = threadIdx.x & 63;
  int sub = lane >> 4;
  int d2 = (lane & 15) * 2;
  int r = gw * 4 + sub;
  if (r >= NN) return;
  int s = offs[r];
  int n = cnt[r];
  float a0 = 0.f, a1 = 0.f;
  int i = 0;
  for (; i + 4 <= n; i += 4) {
    int2 p0 = csr[s + i + 0];
    int2 p1 = csr[s + i + 1];
    int2 p2 = csr[s + i + 2];
    int2 p3 = csr[s + i + 3];
    unsigned int q0 = *(const unsigned int*)&zb[(size_t)p0.x * ZPAD + d2];
    unsigned int q1 = *(const unsigned int*)&zb[(size_t)p1.x * ZPAD + d2];
    unsigned int q2 = *(const unsigned int*)&zb[(size_t)p2.x * ZPAD + d2];
    unsigned int q3 = *(const unsigned int*)&zb[(size_t)p3.x * ZPAD + d2];
    float v0 = __int_as_float(p0.y), v1 = __int_as_float(p1.y);
    float v2 = __int_as_float(p2.y), v3 = __int_as_float(p3.y);
    a0 += v0 * bflo(q0) + v1 * bflo(q1) + v2 * bflo(q2) + v3 * bflo(q3);
    a1 += v0 * bfhi(q0) + v1 * bfhi(q1) + v2 * bfhi(q2) + v3 * bfhi(q3);
  }
  for (; i < n; ++i) {
    int2 p = csr[s + i];
    unsigned int q = *(const unsigned int*)&zb[(size_t)p.x * ZPAD + d2];
    float v = __int_as_float(p.y);
    a0 += v * bflo(q);
    a1 += v * bfhi(q);
  }
  if (d2 < NCLS)     out[(size_t)r * NCLS + d2]     = a0 + b2[d2];
  if (d2 + 1 < NCLS) out[(size_t)r * NCLS + d2 + 1] = a1 + b2[d2 + 1];
}

// ---- Fused MLP via bf16 MFMA: z = relu(ax@W1+b1)@W2, z -> bf16[NN][32] ----
// Block = 128 nodes, 4 waves, hidden chunked x128 (8 chunks).
__global__ __launch_bounds__(256) void fused_mlp_mfma(
    const unsigned short* __restrict__ axg, const unsigned short* __restrict__ w1t,
    const float* __restrict__ b1, const unsigned short* __restrict__ w2t,
    unsigned short* __restrict__ zb) {
  __shared__ __align__(16) unsigned short axs[128 * 104];  // 26.6 KB
  __shared__ __align__(16) unsigned short hs[128 * 136];   // 34.8 KB (chunk 128)
  __shared__ float b1s[DHID];                              // 4 KB
  const int tid = threadIdx.x;
  const int n0 = blockIdx.x * 128;

  for (int idx = tid; idx < 128 * 12; idx += 256) {   // 12 sh8 chunks per row
    int m = idx / 12;
    int c8 = idx - m * 12;
    int node = n0 + m;
    sh8 v = {0, 0, 0, 0, 0, 0, 0, 0};
    if (node < NN) v = *(const sh8*)&axg[(size_t)node * XPAD + c8 * 8];
    *(sh8*)&axs[m * 104 + c8 * 8] = v;
  }
  for (int i = tid; i < DHID; i += 256) b1s[i] = b1[i];
  __syncthreads();

  const int lane = tid & 63;
  const int w = tid >> 6;
  const int quad = lane >> 4;   // A/B frag: k = quad*8 + j
  const int tn = lane & 15;     // A frag: m; B frag: n; C frag: col
  const int mta = w;            // GEMM2 m-tile 1
  const int mtb = w + 4;        // GEMM2 m-tile 2

  sh8 a1[8][3];
#pragma unroll
  for (int mt = 0; mt < 8; ++mt)
#pragma unroll
    for (int kc = 0; kc < 3; ++kc)
      a1[mt][kc] = *(const sh8*)&axs[(mt * 16 + tn) * 104 + kc * 32 + quad * 8];

  f4_t za0 = {0.f, 0.f, 0.f, 0.f}, za1 = {0.f, 0.f, 0.f, 0.f};
  f4_t zb0 = {0.f, 0.f, 0.f, 0.f}, zb1 = {0.f, 0.f, 0.f, 0.f};

  for (int c = 0; c < 8; ++c) {
    const int cb = c * 128;
    // GEMM1: wave w -> n-tiles w*2, w*2+1 ; all 8 m-tiles
#pragma unroll
    for (int nti = 0; nti < 2; ++nti) {
      const int nt = w * 2 + nti;
      const int ng = cb + nt * 16 + tn;
      const unsigned short* wr = &w1t[(size_t)ng * XPAD + quad * 8];
      sh8 b0 = *(const sh8*)&wr[0];
      sh8 b1f = *(const sh8*)&wr[32];
      sh8 b2f = *(const sh8*)&wr[64];
      float bias = b1s[ng];
#pragma unroll
      for (int mt = 0; mt < 8; ++mt) {
        f4_t acc = {0.f, 0.f, 0.f, 0.f};
        acc = __builtin_amdgcn_mfma_f32_16x16x32_bf16(a1[mt][0], b0, acc, 0, 0, 0);
        acc = __builtin_amdgcn_mfma_f32_16x16x32_bf16(a1[mt][1], b1f, acc, 0, 0, 0);
        acc = __builtin_amdgcn_mfma_f32_16x16x32_bf16(a1[mt][2], b2f, acc, 0, 0, 0);
#pragma unroll
        for (int r = 0; r < 4; ++r) {
          float v = relu_(acc[r] + bias);          // C: col=tn, row=quad*4+r
          hs[(mt * 16 + quad * 4 + r) * 136 + nt * 16 + tn] = f2bf(v);
        }
      }
    }
    __syncthreads();
    // GEMM2: z += h_chunk @ W2[cb..cb+127,:]; wave -> m-tiles w, w+4
#pragma unroll
    for (int kc = 0; kc < 4; ++kc) {
      sh8 bl = *(const sh8*)&w2t[(size_t)tn * DHID + cb + kc * 32 + quad * 8];
      sh8 bh = *(const sh8*)&w2t[(size_t)(16 + tn) * DHID + cb + kc * 32 + quad * 8];
      sh8 aa = *(const sh8*)&hs[(mta * 16 + tn) * 136 + kc * 32 + quad * 8];
      za0 = __builtin_amdgcn_mfma_f32_16x16x32_bf16(aa, bl, za0, 0, 0, 0);
      za1 = __builtin_amdgcn_mfma_f32_16x16x32_bf16(aa, bh, za1, 0, 0, 0);
      sh8 ab = *(const sh8*)&hs[(mtb * 16 + tn) * 136 + kc * 32 + quad * 8];
      zb0 = __builtin_amdgcn_mfma_f32_16x16x32_bf16(ab, bl, zb0, 0, 0, 0);
      zb1 = __builtin_amdgcn_mfma_f32_16x16x32_bf16(ab, bh, zb1, 0, 0, 0);
    }
    __syncthreads();
  }

#pragma unroll
  for (int r = 0; r < 4; ++r) {
    int na = n0 + mta * 16 + quad * 4 + r;
    if (na < NN) {
      zb[(size_t)na * ZPAD + tn]      = f2bf(za0[r]);
      zb[(size_t)na * ZPAD + 16 + tn] = f2bf(za1[r]);
    }
    int nb = n0 + mtb * 16 + quad * 4 + r;
    if (nb < NN) {
      zb[(size_t)nb * ZPAD + tn]      = f2bf(zb0[r]);
      zb[(size_t)nb * ZPAD + 16 + tn] = f2bf(zb1[r]);
    }
  }
}

extern "C" void kernel_launch(void* const* d_in, const int* in_sizes, int n_in,
                              void* d_out, int out_size, void* d_ws, size_t ws_size,
                              hipStream_t stream) {
  const float* feature = (const float*)d_in[0];
  const float* conv_w  = (const float*)d_in[1];
  const float* conv_b  = (const float*)d_in[2];
  const float* W1      = (const float*)d_in[3];
  const float* b1      = (const float*)d_in[4];
  const float* W2      = (const float*)d_in[5];
  const float* b2      = (const float*)d_in[6];
  const float* adj     = (const float*)d_in[7];
  const int*   erow    = (const int*)d_in[8];
  const int*   ecol    = (const int*)d_in[9];
  float* out = (float*)d_out;

  char* B = (char*)d_ws;
  size_t o = 0;
  auto alloc = [&](size_t bytes, size_t align) -> void* {
    o = (o + align - 1) & ~(align - 1);
    void* p = B + o;
    o += bytes;
    return p;
  };
  unsigned short* x    = (unsigned short*)alloc((size_t)NN * XPAD * 2, 16);
  unsigned short* ax   = (unsigned short*)alloc((size_t)NN * XPAD * 2, 16);
  unsigned short* zb   = (unsigned short*)alloc((size_t)NN * ZPAD * 2, 16);
  int*   counts  = (int*)alloc((size_t)NN * 4, 16);
  int*   offs    = (int*)alloc((size_t)NN * 4, 16);
  int*   gcur    = (int*)alloc((size_t)NBK * 16 * 4, 64);  // line-padded cursors
  int*   gbk     = (int*)alloc((size_t)NBK * 16 * 4, 64);  // line-padded totals
  int*   bbase   = (int*)alloc((size_t)(NBK + 1) * 4, 16); // bucket bases
  unsigned short* w1t = (unsigned short*)alloc((size_t)DHID * XPAD * 2, 16);
  unsigned short* w2t = (unsigned short*)alloc((size_t)32 * DHID * 2, 16);
  int2*  tmp     = (int2*)alloc((size_t)EE * 8, 16);  // bucket-major
  int2*  csr     = (int2*)alloc((size_t)EE * 8, 16);  // row-sorted

  // 1) x = relu(conv_sum(feature)); weight transposes + gbk zero (merged)
  conv_relu_k<<<8192, 256, 0, stream>>>(feature, conv_w, conv_b, x);
  prep_k<<<(DHID * XPAD + 255) / 256, 256, 0, stream>>>(W1, w1t, W2, w2t, gbk);
  // 2) CSR build: bucket hist -> bucket scan -> direct partition -> fine scatter
  bucket_hist_k<<<(EE + CHUNK - 1) / CHUNK, 512, 0, stream>>>(erow, gbk);
  scan_buckets_k<<<1, 512, 0, stream>>>(gbk, bbase, gcur);
  partition_k<<<(EE + CHUNK - 1) / CHUNK, 256, 0, stream>>>(adj, erow, ecol, gcur, tmp);
  fine_scatter2_k<<<NBK, 512, 0, stream>>>(bbase, tmp, csr, offs, counts);
  // 3) ax = A @ x (gather, bf16 rows, ILP-8, scalar edge loads)
  spmm83_g<<<(NN + 3) / 4, 256, 0, stream>>>(offs, counts, csr, x, ax);
  // 4) z = relu(ax @ W1 + b1) @ W2 via bf16 MFMA (128-node tiles) -> bf16 [NN][32]
  fused_mlp_mfma<<<(NN + 127) / 128, 256, 0, stream>>>(ax, w1t, b1, w2t, zb);
  // 5) out = A @ z + b2 (gather, 1 line per edge, ILP-4)
  spmm25_g<<<(NN + 15) / 16, 256, 0, stream>>>(offs, counts, csr, zb, b2, out);
}